// Round 7
// baseline (175.026 us; speedup 1.0000x reference)
//
#include <hip/hip_runtime.h>

// OmniShift collapsed to one effective 5x5 depthwise conv per channel.
// x: (8, 192, 256, 256) fp32. 805 MB min traffic.
//
// R7: zero-LDS, zero-barrier streaming kernel.
//  R1/R4/R6 (LDS-staged, barrier-phased; 3 different schedules) all converge
//  at 156-158us = 5.2 TB/s. Hypothesis: LDS round-trip + barrier phase-lock
//  caps MLP. This version: one WAVE per (plane, 128-row band), everything in
//  registers, explicit 4-row prefetch ring, no __shared__, no barriers.
//  Horizontal halo via two extra float2 loads (L1-resident lines).
//  Vertical halo: 4 rows per 128 = 3.1% overfetch.

typedef float f32x4 __attribute__((ext_vector_type(4)));
typedef float f32x2 __attribute__((ext_vector_type(2)));

constexpr int Bn = 8, Cn = 192, Hn = 256, Wn = 256;
constexpr int HB = 128;                       // rows per wave
constexpr int NWAVE = Bn * Cn * (Hn / HB);    // 3072 waves
constexpr int NBLK  = NWAVE / 4;              // 768 blocks -> 3/CU, all resident

__global__ __launch_bounds__(256)
void omnishift_kernel(const float* __restrict__ x,
                      const float* __restrict__ w1,
                      const float* __restrict__ w3,
                      const float* __restrict__ w5,
                      const float* __restrict__ alpha,
                      float* __restrict__ out)
{
    const int tid   = threadIdx.x;
    const int wid   = blockIdx.x * 4 + (tid >> 6);
    const int band  = wid & 1;
    const int plane = wid >> 1;              // b*C + c
    const int r0    = band * HB;
    const int c     = plane % Cn;

    // ---- effective 5x5 weights (wave-uniform) ----
    const float a0 = alpha[0], a1 = alpha[1], a2 = alpha[2], a3 = alpha[3];
    float wf[5][5];
#pragma unroll
    for (int i = 0; i < 5; ++i)
#pragma unroll
        for (int j = 0; j < 5; ++j) {
            float v = a3 * w5[(c * 5 + i) * 5 + j];
            if (i >= 1 && i <= 3 && j >= 1 && j <= 3)
                v += a2 * w3[(c * 3 + (i - 1)) * 3 + (j - 1)];
            if (i == 2 && j == 2)
                v += a1 * w1[c] + a0;
            wf[i][j] = v;
        }

    const float* xp = x   + (size_t)plane * (Hn * Wn);
    float*       op = out + (size_t)plane * (Hn * Wn);

    const int   ct    = tid & 63;
    const int   c0    = 4 * ct;
    const float maskL = (ct == 0)  ? 0.f : 1.f;   // cols -2,-1 are padding
    const float maskR = (ct == 63) ? 0.f : 1.f;   // cols 256,257 are padding
    const int   colL  = (c0 - 2 < 0) ? 0 : c0 - 2;
    const int   colR  = (c0 + 4 > Wn - 2) ? Wn - 2 : c0 + 4;

    // issue loads for input row gr (plane coords); row mask for OOB rows
    auto issue = [&](int gr, f32x4& C, f32x2& L, f32x2& R, float& m) {
        int grc = gr < 0 ? 0 : (gr > Hn - 1 ? Hn - 1 : gr);
        m = (gr == grc) ? 1.f : 0.f;
        const float* rp = xp + (size_t)grc * Wn;
        C = *reinterpret_cast<const f32x4*>(rp + c0);
        L = *reinterpret_cast<const f32x2*>(rp + colL);
        R = *reinterpret_cast<const f32x2*>(rp + colR);
    };

    float win[5][8];

    // ---- fill win[0..3] = input rows r0-2 .. r0+1 ----
    {
        f32x4 tC[4]; f32x2 tL[4], tR[4]; float tM[4];
#pragma unroll
        for (int i = 0; i < 4; ++i) issue(r0 - 2 + i, tC[i], tL[i], tR[i], tM[i]);
#pragma unroll
        for (int i = 0; i < 4; ++i) {
            const float ml = maskL * tM[i], mc = tM[i], mr = maskR * tM[i];
            win[i][0] = tL[i].x * ml;  win[i][1] = tL[i].y * ml;
            win[i][2] = tC[i].x * mc;  win[i][3] = tC[i].y * mc;
            win[i][4] = tC[i].z * mc;  win[i][5] = tC[i].w * mc;
            win[i][6] = tR[i].x * mr;  win[i][7] = tR[i].y * mr;
        }
    }

    // ---- prefetch ring: slots 0..3 <- input rows r0+2 .. r0+5 ----
    f32x4 sC[4]; f32x2 sL[4], sR[4]; float sM[4];
#pragma unroll
    for (int i = 0; i < 4; ++i) issue(r0 + 2 + i, sC[i], sL[i], sR[i], sM[i]);

#pragma unroll 1
    for (int rb = 0; rb < HB; rb += 4) {
#pragma unroll
        for (int u = 0; u < 4; ++u) {
            const int r = rb + u;

            // consume slot u = input row r0+r+2 -> win[4]
            const float ml = maskL * sM[u], mc = sM[u], mr = maskR * sM[u];
            win[4][0] = sL[u].x * ml;  win[4][1] = sL[u].y * ml;
            win[4][2] = sC[u].x * mc;  win[4][3] = sC[u].y * mc;
            win[4][4] = sC[u].z * mc;  win[4][5] = sC[u].w * mc;
            win[4][6] = sR[u].x * mr;  win[4][7] = sR[u].y * mr;

            // compute output row r0+r
            f32x4 o;
#pragma unroll
            for (int j = 0; j < 4; ++j) {
                float acc = 0.f;
#pragma unroll
                for (int i = 0; i < 5; ++i)
#pragma unroll
                    for (int d = 0; d < 5; ++d)
                        acc += win[i][j + d] * wf[i][d];
                o[j] = acc;
            }
            *reinterpret_cast<f32x4*>(op + (size_t)(r0 + r) * Wn + c0) = o;

            // re-issue slot u <- input row r0+r+6 (clamped+masked past end)
            issue(r0 + r + 6, sC[u], sL[u], sR[u], sM[u]);

            // slide window (static indices -> register renaming)
#pragma unroll
            for (int i = 0; i < 4; ++i)
#pragma unroll
                for (int j = 0; j < 8; ++j) win[i][j] = win[i + 1][j];
        }
    }
}

extern "C" void kernel_launch(void* const* d_in, const int* in_sizes, int n_in,
                              void* d_out, int out_size, void* d_ws, size_t ws_size,
                              hipStream_t stream)
{
    const float* x     = (const float*)d_in[0];
    const float* w1    = (const float*)d_in[1];
    const float* w3    = (const float*)d_in[2];
    const float* w5    = (const float*)d_in[3];
    const float* alpha = (const float*)d_in[4];
    float* out = (float*)d_out;

    omnishift_kernel<<<NBLK, 256, 0, stream>>>(x, w1, w3, w5, alpha, out);
}